// Round 5
// baseline (308.901 us; speedup 1.0000x reference)
//
#include <hip/hip_runtime.h>

// Problem constants: B=2, S=2048, D=1024, H=16, DH=64
constexpr int BB = 2, SS = 2048, DD = 1024, HH = 16, DHH = 64;

typedef __attribute__((ext_vector_type(4))) float f32x4;
typedef __attribute__((ext_vector_type(8))) __bf16 bf16x8;      // 4 VGPRs, MFMA A/B operand
typedef __attribute__((ext_vector_type(8))) unsigned short us8; // 16B staging vector

__device__ __forceinline__ unsigned short f32_to_bf16(float f) {
    unsigned int u = __float_as_uint(f);
    u += 0x7fffu + ((u >> 16) & 1u);   // round-to-nearest-even
    return (unsigned short)(u >> 16);
}

// packed f32x2 -> bf16x2 (RNE); gfx950 has v_cvt_pk_bf16_f32
__device__ __forceinline__ ushort2 pk_bf16(float a, float b) {
#if __has_builtin(__builtin_amdgcn_cvt_pk_bf16_f32)
    typedef __attribute__((ext_vector_type(2))) __bf16 bf16x2;
    bf16x2 r = __builtin_amdgcn_cvt_pk_bf16_f32(a, b);
    return *(ushort2*)&r;
#else
    ushort2 r; r.x = f32_to_bf16(a); r.y = f32_to_bf16(b); return r;
#endif
}
__device__ __forceinline__ ushort4 pk_bf16x4(float a, float b, float c, float d) {
    const ushort2 lo = pk_bf16(a, b), hi = pk_bf16(c, d);
    ushort4 r; r.x = lo.x; r.y = lo.y; r.z = hi.x; r.w = hi.y;
    return r;
}
__device__ __forceinline__ us8 cvt_us8(float4 a, float4 b) {
    const ushort4 lo = pk_bf16x4(a.x, a.y, a.z, a.w);
    const ushort4 hi = pk_bf16x4(b.x, b.y, b.z, b.w);
    us8 o;
    o[0] = lo.x; o[1] = lo.y; o[2] = lo.z; o[3] = lo.w;
    o[4] = hi.x; o[5] = hi.y; o[6] = hi.z; o[7] = hi.w;
    return o;
}

__device__ __forceinline__ f32x4 mfma_bf16(bf16x8 a, bf16x8 b, f32x4 c) {
    return __builtin_amdgcn_mfma_f32_16x16x32_bf16(a, b, c, 0, 0, 0);
}

// async global->LDS DMA, 16B per lane. LDS dest = wave-uniform base + lane*16.
__device__ __forceinline__ void stage16(const void* g, void* l) {
    typedef const __attribute__((address_space(1))) unsigned int gas_t;
    typedef __attribute__((address_space(3))) unsigned int las_t;
    __builtin_amdgcn_global_load_lds((gas_t*)(unsigned long long)g,
                                     (las_t*)(unsigned int)(unsigned long long)l,
                                     16, 0, 0);
}

// ---------------------------------------------------------------------------
// cvt helper: fp32 -> bf16, 8 elements/thread, one 2048-element block `blk`
// ---------------------------------------------------------------------------
__device__ __forceinline__ void cvt_block(const float* __restrict__ src,
                                          unsigned short* __restrict__ dst, int blk) {
    const size_t i = ((size_t)blk * 256 + threadIdx.x) * 8;
    const float4 a = *(const float4*)(src + i);
    const float4 b = *(const float4*)(src + i + 4);
    *(us8*)(dst + i) = cvt_us8(a, b);
}

// standalone cvt (used for Wo after flash)
__global__ __launch_bounds__(256) void cvt_bf16(const float* __restrict__ src,
                                                unsigned short* __restrict__ dst) {
    cvt_block(src, dst, blockIdx.x);
}

// ---------------------------------------------------------------------------
// prep: pre-gemm prep in one launch (value_ is NOT converted — the V gemm
// stages f32 directly).
//   blocks [0,2048):     cvt query
//   blocks [2048,4096):  cvt key
//   blocks [4096,5632):  cvt Wq/Wk/Wv (512 each)
//   blocks [5632,13824): mask pack (8192 blocks x 16 chunks)
// ---------------------------------------------------------------------------
__global__ __launch_bounds__(256) void prep(const float* __restrict__ q,
                                            const float* __restrict__ k,
                                            const float* __restrict__ Wq,
                                            const float* __restrict__ Wk,
                                            const float* __restrict__ Wv,
                                            unsigned short* __restrict__ Xq,
                                            unsigned short* __restrict__ Xk,
                                            unsigned short* __restrict__ Wqb,
                                            unsigned short* __restrict__ Wkb,
                                            unsigned short* __restrict__ Wvb,
                                            const int* __restrict__ mask,
                                            unsigned long long* __restrict__ pm) {
    const int id = blockIdx.x;
    if (id < 4096) {
        const int sel = id >> 11, blk = id & 2047;
        cvt_block(sel == 0 ? q : k, sel == 0 ? Xq : Xk, blk);
    } else if (id < 5632) {
        const int wid = id - 4096;
        const int sel = wid >> 9, blk = wid & 511;
        cvt_block(sel == 0 ? Wq : (sel == 1 ? Wk : Wv),
                  sel == 0 ? Wqb : (sel == 1 ? Wkb : Wvb), blk);
    } else {
        const int mid = id - 5632;
        const int t = threadIdx.x, lane = t & 63;
#pragma unroll
        for (int it = 0; it < 4; ++it) {
            const size_t chunk = (size_t)mid * 16 + it * 4 + (t >> 6);
            const int val = mask[chunk * 64 + lane];
            const unsigned long long b = __ballot(val != 0);
            if (lane == 0) pm[chunk] = b;
        }
    }
}

// ---------------------------------------------------------------------------
// Fused Q/K/V projection GEMM: 128x128 tile, BK=64, 8 waves (2x4 wave grid,
// each wave 64x32 output). Double-buffered staging: Q/K/weights via
// global_load_lds DMA (4/thread/K-step, counted vmcnt(4)); V's A-operand is
// reg-staged from f32 (load f32 -> cvt_pk -> swizzled ds_write, vmcnt(6)
// keeps B-DMA flying, lgkmcnt(0) before tail barrier). Chunk-XOR swizzle
// everywhere (linear DMA dest + pre-swizzled source; reg path writes the
// swizzled slot directly). setprio around MFMA.
// Outputs: Q/K -> (B,H,S,DH) bf16 scatter (+ head-0 copies); V -> (B,H,DH,S)
// via per-wave LDS transpose -> coalesced 16B stores.
// Grid: 768 blocks, XCD-chunked bijective (which=Q/K/V slowest).
// ---------------------------------------------------------------------------
__global__ __launch_bounds__(512) void gemm_qkv(
    const unsigned short* __restrict__ Xq, const unsigned short* __restrict__ Xk,
    const float* __restrict__ Vf,
    const unsigned short* __restrict__ Wqb, const unsigned short* __restrict__ Wkb,
    const unsigned short* __restrict__ Wvb,
    const float* __restrict__ bq, const float* __restrict__ bk,
    const float* __restrict__ bv,
    unsigned short* __restrict__ qws, unsigned short* __restrict__ kws,
    unsigned short* __restrict__ vws,
    unsigned short* __restrict__ q0, unsigned short* __restrict__ k0,
    float qscale) {
    constexpr int K = DD;
    __shared__ __align__(16) unsigned short AB[2][2][128][64];  // [A/B][dbuf][row][col]

    const int id = blockIdx.x;
    const int nid = (id & 7) * 96 + (id >> 3);     // bijective XCD chunking
    const int which = nid >> 8;                    // 0=Q 1=K 2=V
    const int r8 = nid & 255;
    const int m0 = (r8 >> 3) * 128;
    const int n0 = (r8 & 7) * 128;

    const int t = threadIdx.x;
    const int lane = t & 63, w = t >> 6;
    const int l15 = lane & 15, quad = lane >> 4;
    const int wm = (w >> 2) * 64, wn = (w & 3) * 32;
    const bool vp = (which == 2);

    const unsigned short* Ab = which == 0 ? Xq : Xk;
    const unsigned short* Wb = which == 0 ? Wqb : (which == 1 ? Wkb : Wvb);
    const float* bias = which == 0 ? bq : (which == 1 ? bk : bv);
    const float scale = which == 0 ? qscale : 1.0f;

    // DMA source (pre-swizzled): per issue j, lane covers row j*64+w*8+(l>>3),
    // LDS chunk l&7; source chunk = (l&7) ^ (row&7).
    const int srow = lane >> 3;
    const int scol8 = ((lane & 7) ^ srow) * 8;
    const unsigned short* Agp = Ab + (size_t)(m0 + w * 8 + srow) * K + scol8;
    const unsigned short* Bgp = Wb + (size_t)(n0 + w * 8 + srow) * K + scol8;

    // V reg-staging: thread slot j -> row j*64+(t>>3), chunk t&7
    const int vrow = t >> 3, vc = t & 7;
    const float* Vg = Vf + (size_t)(m0 + vrow) * K + vc * 8;

    f32x4 acc[4][2] = {};
    float4 va0, va1, va2, va3;                     // V A-tile in flight

    // ---- prologue: tile 0 -> buf 0 ----
    if (!vp) {
#pragma unroll
        for (int j = 0; j < 2; ++j) {
            stage16(Agp + (size_t)(j * 64) * K, &AB[0][0][w * 8 + j * 64][0]);
            stage16(Bgp + (size_t)(j * 64) * K, &AB[1][0][w * 8 + j * 64][0]);
        }
    } else {
        va0 = *(const float4*)(Vg);
        va1 = *(const float4*)(Vg + 4);
        va2 = *(const float4*)(Vg + (size_t)64 * K);
        va3 = *(const float4*)(Vg + (size_t)64 * K + 4);
#pragma unroll
        for (int j = 0; j < 2; ++j)
            stage16(Bgp + (size_t)(j * 64) * K, &AB[1][0][w * 8 + j * 64][0]);
        {
            const int wr0 = vrow, wr1 = 64 + vrow;
            *(us8*)((unsigned char*)&AB[0][0][0][0] + wr0 * 128 + ((vc ^ (wr0 & 7)) * 16))
                = cvt_us8(va0, va1);
            *(us8*)((unsigned char*)&AB[0][0][0][0] + wr1 * 128 + ((vc ^ (wr1 & 7)) * 16))
                = cvt_us8(va2, va3);
        }
        __asm__ volatile("s_waitcnt lgkmcnt(0)" ::: "memory");
    }

    for (int kk = 0; kk < K / 64; ++kk) {
        const int cur = kk & 1;
        if (kk < K / 64 - 1) {
            const size_t ko = (size_t)(kk + 1) * 64;
            if (!vp) {
#pragma unroll
                for (int j = 0; j < 2; ++j) {
                    stage16(Agp + (size_t)(j * 64) * K + ko, &AB[0][cur ^ 1][w * 8 + j * 64][0]);
                    stage16(Bgp + (size_t)(j * 64) * K + ko, &AB[1][cur ^ 1][w * 8 + j * 64][0]);
                }
                __asm__ volatile("s_waitcnt vmcnt(4)" ::: "memory");
            } else {
                va0 = *(const float4*)(Vg + ko);
                va1 = *(const float4*)(Vg + ko + 4);
                va2 = *(const float4*)(Vg + (size_t)64 * K + ko);
                va3 = *(const float4*)(Vg + (size_t)64 * K + ko + 4);
#pragma unroll
                for (int j = 0; j < 2; ++j)
                    stage16(Bgp + (size_t)(j * 64) * K + ko, &AB[1][cur ^ 1][w * 8 + j * 64][0]);
                // outstanding: old-B(2) + A-regs(4) + new-B(2) -> keep 6 newest
                __asm__ volatile("s_waitcnt vmcnt(6)" ::: "memory");
            }
        } else {
            __asm__ volatile("s_waitcnt vmcnt(0)" ::: "memory");
        }
        __builtin_amdgcn_s_barrier();
        __builtin_amdgcn_sched_barrier(0);

#pragma unroll
        for (int s = 0; s < 2; ++s) {
            const int ch = ((s * 4 + quad) ^ (l15 & 7)) * 8;
            bf16x8 af[4], bfr[2];
#pragma unroll
            for (int mi = 0; mi < 4; ++mi)
                af[mi] = *(const bf16x8*)&AB[0][cur][wm + mi * 16 + l15][ch];
#pragma unroll
            for (int ni = 0; ni < 2; ++ni)
                bfr[ni] = *(const bf16x8*)&AB[1][cur][wn + ni * 16 + l15][ch];
            __builtin_amdgcn_s_setprio(1);
#pragma unroll
            for (int mi = 0; mi < 4; ++mi)
#pragma unroll
                for (int ni = 0; ni < 2; ++ni)
                    acc[mi][ni] = mfma_bf16(af[mi], bfr[ni], acc[mi][ni]);
            __builtin_amdgcn_s_setprio(0);
        }

        if (vp && kk < K / 64 - 1) {
            // commit A(kk+1) to buf^1 (compiler drains the 4 f32 loads only)
            const int wr0 = vrow, wr1 = 64 + vrow;
            *(us8*)((unsigned char*)&AB[0][cur ^ 1][0][0] + wr0 * 128 + ((vc ^ (wr0 & 7)) * 16))
                = cvt_us8(va0, va1);
            *(us8*)((unsigned char*)&AB[0][cur ^ 1][0][0] + wr1 * 128 + ((vc ^ (wr1 & 7)) * 16))
                = cvt_us8(va2, va3);
            __asm__ volatile("s_waitcnt lgkmcnt(0)" ::: "memory");
        }

        __builtin_amdgcn_sched_barrier(0);
        __builtin_amdgcn_s_barrier();
        __builtin_amdgcn_sched_barrier(0);
    }

    if (which < 2) {
        unsigned short* o = which == 0 ? qws : kws;
        unsigned short* h0 = which == 0 ? q0 : k0;
#pragma unroll
        for (int ni = 0; ni < 2; ++ni) {
            const int c = n0 + wn + ni * 16 + l15;
            const float bs = bias[c];
            const int hi2 = c >> 6, di = c & (DHH - 1);
#pragma unroll
            for (int mi = 0; mi < 4; ++mi) {
#pragma unroll
                for (int r = 0; r < 4; ++r) {
                    const int mrow = m0 + wm + mi * 16 + quad * 4 + r;
                    const int bi2 = mrow >> 11, si = mrow & (SS - 1);
                    const unsigned short v16 = f32_to_bf16((acc[mi][ni][r] + bs) * scale);
                    o[((size_t)(bi2 * HH + hi2) * SS + si) * DHH + di] = v16;
                    if (hi2 == 0)
                        h0[((size_t)bi2 * SS + si) * DHH + di] = v16;
                }
            }
        }
    } else {
        // V: per-wave LDS transpose -> coalesced 16B stores along S.
        // Safe to reuse AB: all waves passed the final tail barrier, and each
        // wave touches only its own scratch slice.
        unsigned short* scr = (unsigned short*)&AB[0][0][0][0] + w * (32 * 72);
#pragma unroll
        for (int ni = 0; ni < 2; ++ni) {
            const int c = n0 + wn + ni * 16 + l15;
            const float bs = bias[c];
#pragma unroll
            for (int mi = 0; mi < 4; ++mi)
                *(ushort4*)&scr[(ni * 16 + l15) * 72 + mi * 16 + quad * 4] =
                    pk_bf16x4(acc[mi][ni][0] + bs, acc[mi][ni][1] + bs,
                              acc[mi][ni][2] + bs, acc[mi][ni][3] + bs);
        }
        __asm__ volatile("s_waitcnt lgkmcnt(0)" ::: "memory");  // wave-local RAW
        const int mb = m0 + wm;                   // 64-row (si) block base
        const int bi2 = mb >> 11, si0 = mb & (SS - 1);
        const int rowc = lane & 7;
#pragma unroll
        for (int k2 = 0; k2 < 4; ++k2) {
            const int col = k2 * 8 + (lane >> 3);
            const us8 vv = *(const us8*)&scr[col * 72 + rowc * 8];
            const int c = n0 + wn + col;
            *(us8*)&vws[((size_t)(bi2 * HH + (c >> 6)) * DHH + (c & 63)) * SS
                        + si0 + rowc * 8] = vv;
        }
    }
}

// ---------------------------------------------------------------------------
// Output projection GEMM: same 128x128 8-wave body, bf16 DMA staging,
// f32 (B,S,D) output. Grid: 256 blocks, XCD-chunked.
// ---------------------------------------------------------------------------
__global__ __launch_bounds__(512) void gemm_o(const unsigned short* __restrict__ A,
                                              const unsigned short* __restrict__ Wb,
                                              const float* __restrict__ bias,
                                              float* __restrict__ outp) {
    constexpr int K = DD;
    __shared__ __align__(16) unsigned short AB[2][2][128][64];

    const int id = blockIdx.x;
    const int nid = (id & 7) * 32 + (id >> 3);
    const int m0 = (nid >> 3) * 128;
    const int n0 = (nid & 7) * 128;

    const int t = threadIdx.x;
    const int lane = t & 63, w = t >> 6;
    const int l15 = lane & 15, quad = lane >> 4;
    const int wm = (w >> 2) * 64, wn = (w & 3) * 32;

    const int srow = lane >> 3;
    const int scol8 = ((lane & 7) ^ srow) * 8;
    const unsigned short* Agp = A + (size_t)(m0 + w * 8 + srow) * K + scol8;
    const unsigned short* Bgp = Wb + (size_t)(n0 + w * 8 + srow) * K + scol8;

    f32x4 acc[4][2] = {};

#pragma unroll
    for (int j = 0; j < 2; ++j) {
        stage16(Agp + (size_t)(j * 64) * K, &AB[0][0][w * 8 + j * 64][0]);
        stage16(Bgp + (size_t)(j * 64) * K, &AB[1][0][w * 8 + j * 64][0]);
    }

    for (int kk = 0; kk < K / 64; ++kk) {
        const int cur = kk & 1;
        if (kk < K / 64 - 1) {
            const size_t ko = (size_t)(kk + 1) * 64;
#pragma unroll
            for (int j = 0; j < 2; ++j) {
                stage16(Agp + (size_t)(j * 64) * K + ko, &AB[0][cur ^ 1][w * 8 + j * 64][0]);
                stage16(Bgp + (size_t)(j * 64) * K + ko, &AB[1][cur ^ 1][w * 8 + j * 64][0]);
            }
            __asm__ volatile("s_waitcnt vmcnt(4)" ::: "memory");
        } else {
            __asm__ volatile("s_waitcnt vmcnt(0)" ::: "memory");
        }
        __builtin_amdgcn_s_barrier();
        __builtin_amdgcn_sched_barrier(0);

#pragma unroll
        for (int s = 0; s < 2; ++s) {
            const int ch = ((s * 4 + quad) ^ (l15 & 7)) * 8;
            bf16x8 af[4], bfr[2];
#pragma unroll
            for (int mi = 0; mi < 4; ++mi)
                af[mi] = *(const bf16x8*)&AB[0][cur][wm + mi * 16 + l15][ch];
#pragma unroll
            for (int ni = 0; ni < 2; ++ni)
                bfr[ni] = *(const bf16x8*)&AB[1][cur][wn + ni * 16 + l15][ch];
            __builtin_amdgcn_s_setprio(1);
#pragma unroll
            for (int mi = 0; mi < 4; ++mi)
#pragma unroll
                for (int ni = 0; ni < 2; ++ni)
                    acc[mi][ni] = mfma_bf16(af[mi], bfr[ni], acc[mi][ni]);
            __builtin_amdgcn_s_setprio(0);
        }
        __builtin_amdgcn_sched_barrier(0);
        __builtin_amdgcn_s_barrier();
        __builtin_amdgcn_sched_barrier(0);
    }

#pragma unroll
    for (int ni = 0; ni < 2; ++ni) {
        const int c = n0 + wn + ni * 16 + l15;
        const float bs = bias[c];
#pragma unroll
        for (int mi = 0; mi < 4; ++mi)
#pragma unroll
            for (int r = 0; r < 4; ++r) {
                const int mrow = m0 + wm + mi * 16 + quad * 4 + r;
                outp[(size_t)mrow * DD + c] = acc[mi][ni][r] + bs;
            }
    }
}

// ---------------------------------------------------------------------------
// Flash attention v6 (verified R3/R4): 8 waves, 128 q-rows/block, 16/wave;
// K/V double-buffered via global_load_lds + counted vmcnt(3); chunk-XOR
// swizzle; setprio on MFMA; defer-max (T13); head-0 (M,L) stats export;
// XCD-chunked block swizzle.
// ---------------------------------------------------------------------------
__global__ __launch_bounds__(512, 4) void flash_attn(const unsigned short* __restrict__ qws,
                                                     const unsigned short* __restrict__ kws,
                                                     const unsigned short* __restrict__ vws,
                                                     const unsigned long long* __restrict__ pm,
                                                     unsigned short* __restrict__ ctx,
                                                     float2* __restrict__ stats) {
    __shared__ __align__(16) unsigned short Ksh[2][64][64];   // [key][d], swizzled
    __shared__ __align__(16) unsigned short Vsh[2][64][64];   // [d][key], swizzled
    __shared__ __align__(16) unsigned short Psh[8][16][72];   // per-wave [q][key]

    constexpr int NQT = SS / 128;                  // 16
    const int id = blockIdx.x;
    const int nid = (id & 7) * 64 + (id >> 3);
    const int qt = nid % NQT;
    const int bh = nid / NQT;
    const int bi = bh / HH, hi = bh % HH;

    const int t = threadIdx.x;
    const int lane = t & 63, w = t >> 6;           // w in 0..7
    const int l15 = lane & 15, quad = lane >> 4;
    const int sh4 = quad * 4;
    const int xk = quad ^ (l15 & 7);               // swizzled chunk for fragment reads

    const unsigned short* qp = qws + (size_t)bh * SS * DHH;
    const unsigned short* kp = kws + (size_t)bh * SS * DHH;
    const unsigned short* vp = vws + (size_t)bh * DHH * SS;

    const int q_loc = qt * 128 + w * 16 + l15;
    const bf16x8 bq0 = *(const bf16x8*)(qp + (size_t)q_loc * DHH + quad * 8);
    const bf16x8 bq1 = *(const bf16x8*)(qp + (size_t)q_loc * DHH + 32 + quad * 8);
    const unsigned long long* pmrow = pm + ((size_t)bi * SS + q_loc) * (SS / 64);

    // staging source (pre-swizzled): lane l writes LDS chunk w*64+l linearly;
    // its content must be source chunk (row, c ^ (row&7)).
    const int srow = lane >> 3;            // row within wave's 8-row stripe
    const int scol = (lane & 7) ^ srow;    // pre-swizzled source chunk
    const unsigned short* kg = kp + (size_t)(w * 8 + srow) * DHH + scol * 8;
    const unsigned short* vg = vp + (size_t)(w * 8 + srow) * SS + scol * 8;

    f32x4 accO[4] = {};                    // O^T: d = 16i+quad*4+r, q = l15
    float m_run = -1e30f, l_run = 0.f;
    const float NEG_INF = -__builtin_inff();

    unsigned long long mcur = pmrow[0];
    stage16(kg, &Ksh[0][w * 8][0]);        // tile 0 in flight
    stage16(vg, &Vsh[0][w * 8][0]);

    constexpr int NT = SS / 64;
    for (int kt = 0; kt < NT; ++kt) {
        const int cur = kt & 1;
        unsigned long long mnxt = 0;
        if (kt < NT - 1) {
            mnxt = pmrow[kt + 1];                                        // VMEM op #1
            stage16(kg + (size_t)(kt + 1) * 64 * DHH, &Ksh[cur ^ 1][w * 8][0]); // #2
            stage16(vg + (size_t)(kt + 1) * 64,       &Vsh[cur ^ 1][w * 8][0]); // #3
            // wait own current-tile DMA (leave the 3 newest in flight)
            __asm__ volatile("s_waitcnt vmcnt(3)" ::: "memory");
        } else {
            __asm__ volatile("s_waitcnt vmcnt(0)" ::: "memory");
        }
        __builtin_amdgcn_s_barrier();          // everyone's current tile landed
        __builtin_amdgcn_sched_barrier(0);     // no LDS reads hoist above this

        const unsigned short* Kb = &Ksh[cur][0][0];
        const unsigned short* Vb = &Vsh[cur][0][0];

        bf16x8 ak0[4], ak1[4];
#pragma unroll
        for (int i = 0; i < 4; ++i) {
            ak0[i] = *(const bf16x8*)&Kb[(i * 16 + l15) * 64 + xk * 8];
            ak1[i] = *(const bf16x8*)&Kb[(i * 16 + l15) * 64 + (xk ^ 4) * 8];
        }

        const unsigned int mlo = ((unsigned int)mcur) >> sh4;
        const unsigned int mhi = ((unsigned int)(mcur >> 32)) >> sh4;

        // S^T: key = kt*64 + 16i + quad*4 + r, q = l15
        float sc[4][4];
        __builtin_amdgcn_s_setprio(1);
#pragma unroll
        for (int i = 0; i < 4; ++i) {
            f32x4 s4 = {};
            s4 = mfma_bf16(ak0[i], bq0, s4);
            s4 = mfma_bf16(ak1[i], bq1, s4);
            const unsigned int mw = (i & 2) ? mhi : mlo;
#pragma unroll
            for (int r = 0; r < 4; ++r)
                sc[i][r] = ((mw >> ((i & 1) * 16 + r)) & 1u) ? NEG_INF : s4[r];
        }
        __builtin_amdgcn_s_setprio(0);

        // issue V fragment reads early; latency hides under softmax VALU
        bf16x8 av0[4], av1[4];
#pragma unroll
        for (int i = 0; i < 4; ++i) {
            av0[i] = *(const bf16x8*)&Vb[(i * 16 + l15) * 64 + xk * 8];
            av1[i] = *(const bf16x8*)&Vb[(i * 16 + l15) * 64 + (xk ^ 4) * 8];
        }

        // online softmax for q = l15 (base-2; scores carry log2e)
        float tm = sc[0][0];
#pragma unroll
        for (int i = 0; i < 4; ++i)
#pragma unroll
            for (int r = 0; r < 4; ++r) tm = fmaxf(tm, sc[i][r]);
        tm = fmaxf(tm, __shfl_xor(tm, 16));
        tm = fmaxf(tm, __shfl_xor(tm, 32));

        // defer-max (T13): if no q-row's tile-max exceeds m_run+8, keep the
        // old max -> skip accO rescale. P bounded by 2^8 (safe in bf16).
        const bool nodefer = !__all(tm <= m_run + 8.0f);
        const float mn = nodefer ? fmaxf(m_run, tm) : m_run;

        float rs = 0.f;
#pragma unroll
        for (int i = 0; i < 4; ++i)
#pragma unroll
            for (int r = 0; r < 4; ++r) {
                const float p = __builtin_amdgcn_exp2f(sc[i][r] - mn);
                sc[i][r] = p;
                rs += p;
            }
        rs += __shfl_xor(rs, 16);
        rs += __shfl_xor(rs, 32);

        if (nodefer) {                         // wave-uniform branch
            const float alpha = __builtin_amdgcn_exp2f(m_run - mn);
            l_run = l_run * alpha + rs;
            m_run = mn;
#pragma unroll
            for (int i = 0; i < 4; ++i) accO[i] *= alpha;
        } else {
            l_run += rs;
        }

        // P store: lane's 4 consecutive keys -> one b64 per i (wave-private)
#pragma unroll
        for (int i = 0; i < 4; ++i)
            *(ushort4*)&Psh[w][l15][i * 16 + sh4] =
                pk_bf16x4(sc[i][0], sc[i][1], sc[i][2], sc[i][3]);
        __asm__ volatile("s_waitcnt lgkmcnt(0)" ::: "memory");  // wave-local RAW

        const bf16x8 p0 = *(const bf16x8*)&Psh[w][l15][quad * 8];
        const bf16x8 p1 = *(const bf16x8*)&Psh[w][l15][32 + quad * 8];
        __builtin_amdgcn_s_setprio(1);
#pragma unroll
        for (int i = 0; i < 4; ++i) {
            accO[i] = mfma_bf16(av0[i], p0, accO[i]);   // O^T[d][q]
            accO[i] = mfma_bf16(av1[i], p1, accO[i]);
        }
        __builtin_amdgcn_s_setprio(0);

        __builtin_amdgcn_sched_barrier(0);     // nothing sinks below this point
        __builtin_amdgcn_s_barrier();          // all reads of buf[cur] done
        __builtin_amdgcn_sched_barrier(0);     // next iter's VMEM stays below
        mcur = mnxt;
    }

    // epilogue
    const float inv = 1.0f / l_run;
    unsigned short* cb = ctx + ((size_t)(bi * SS) + q_loc) * DD + hi * DHH;
#pragma unroll
    for (int i = 0; i < 4; ++i)
        *(ushort4*)&cb[i * 16 + sh4] = pk_bf16x4(accO[i][0] * inv, accO[i][1] * inv,
                                                 accO[i][2] * inv, accO[i][3] * inv);

    // head-0: export softmax stats (M, L). p = exp2(s - M)/L is exact even
    // with deferred M (both offsets cancel).
    if (hi == 0 && quad == 0) {
        float2 st; st.x = m_run; st.y = l_run;
        stats[(size_t)bi * SS + q_loc] = st;
    }
}

// ---------------------------------------------------------------------------
// prob_h0: head-0 final attention probabilities in ONE pass, using flash's
// (M, L) stats. Same bf16 operands + MFMA order as flash -> bit-identical
// scores. Masked -> exactly 0.
// Grid: 512 blocks (B * 32 q-tiles * 8 key-chunks of 256).
// ---------------------------------------------------------------------------
__global__ __launch_bounds__(256) void prob_h0(const unsigned short* __restrict__ q0,
                                               const unsigned short* __restrict__ k0,
                                               const unsigned long long* __restrict__ pm,
                                               const float2* __restrict__ stats,
                                               float* __restrict__ outp) {
    __shared__ __align__(16) unsigned short Ksh[64][72];

    const int id = blockIdx.x;
    const int nid = (id & 7) * 64 + (id >> 3);     // XCD-chunked, bijective
    const int kc = nid & 7;                        // key chunk (256 keys)
    const int qt = (nid >> 3) & 31;                // q tile
    const int bi = nid >> 8;                       // batch

    const int t = threadIdx.x;
    const int lane = t & 63, w = t >> 6;
    const int l15 = lane & 15, quad = lane >> 4;
    const int sh4 = quad * 4;

    const int q = qt * 64 + w * 16 + l15;      // this lane's q row
    const unsigned short* qp = q0 + ((size_t)bi * SS + q) * DHH;
    const bf16x8 bq0 = *(const bf16x8*)(qp + quad * 8);
    const bf16x8 bq1 = *(const bf16x8*)(qp + 32 + quad * 8);

    const unsigned short* kp = k0 + (size_t)bi * SS * DHH;
    const unsigned long long* pmq = pm + ((size_t)bi * SS + q) * (SS / 64);
    float* orow = outp + ((size_t)bi * SS + q) * SS;

    const float2 st = stats[(size_t)bi * SS + q];
    const float M = st.x;
    const float invL = 1.0f / st.y;

    for (int kt = 0; kt < 4; ++kt) {
        const int key0 = kc * 256 + kt * 64;
        __syncthreads();
#pragma unroll
        for (int hf = 0; hf < 2; ++hf) {
            const int v = t + hf * 256;
            const int row = v >> 3, off = (v & 7) * 8;
            *(us8*)&Ksh[row][off] = *(const us8*)(kp + (size_t)(key0 + row) * DHH + off);
        }
        __syncthreads();

        const unsigned long long m64 = pmq[kc * 4 + kt];
        const unsigned int mlo = ((unsigned int)m64) >> sh4;
        const unsigned int mhi = ((unsigned int)(m64 >> 32)) >> sh4;

#pragma unroll
        for (int i = 0; i < 4; ++i) {
            const bf16x8 ak0 = *(const bf16x8*)&Ksh[i * 16 + l15][quad * 8];
            const bf16x8 ak1 = *(const bf16x8*)&Ksh[i * 16 + l15][32 + quad * 8];
            f32x4 s4 = {};
            s4 = mfma_bf16(ak0, bq0, s4);
            s4 = mfma_bf16(ak1, bq1, s4);
            const unsigned int mw = (i & 2) ? mhi : mlo;
            float4 ov;
#pragma unroll
            for (int r = 0; r < 4; ++r) {
                const float p = __builtin_amdgcn_exp2f(s4[r] - M) * invL;
                ((float*)&ov)[r] = ((mw >> ((i & 1) * 16 + r)) & 1u) ? 0.0f : p;
            }
            *(float4*)&orow[key0 + i * 16 + sh4] = ov;
        }
    }
}

// ---------------------------------------------------------------------------
// inputs: 0 key, 1 value, 2 query, 3 mask, 4 Wk, 5 bk, 6 Wv, 7 bv,
//         8 Wq, 9 bq, 10 Wo, 11 bo
// d_out: output (B*S*D f32, 16 MB) ++ top_attn (B*S*S f32, 32 MB)
// d_ws (~2.13 MB): head-0 q/k (1 MB) + packed mask bits (1 MB) + stats (32 KB)
// Graph: 6 nodes (prep, gemm_qkv, flash, cvt_Wo, gemm_o, prob_h0).
// ---------------------------------------------------------------------------
extern "C" void kernel_launch(void* const* d_in, const int* in_sizes, int n_in,
                              void* d_out, int out_size, void* d_ws, size_t ws_size,
                              hipStream_t stream) {
    const float* key_   = (const float*)d_in[0];
    const float* value_ = (const float*)d_in[1];
    const float* query_ = (const float*)d_in[2];
    const int*   mask_  = (const int*)d_in[3];
    const float* Wk = (const float*)d_in[4];
    const float* bk = (const float*)d_in[5];
    const float* Wv = (const float*)d_in[6];
    const float* bv = (const float*)d_in[7];
    const float* Wq = (const float*)d_in[8];
    const float* bq = (const float*)d_in[9];
    const float* Wo = (const float*)d_in[10];
    const float* bo = (const float*)d_in[11];

    constexpr size_t XS  = (size_t)BB * SS * DD;  // 4194304 elements
    constexpr size_t WSZ = (size_t)DD * DD;       // 1048576 elements

    float* out_f = (float*)d_out;
    unsigned short* scratch = (unsigned short*)(out_f + XS);
    unsigned short* qws = scratch;            // (B,H,S,DH)
    unsigned short* kws = qws + XS;           // (B,H,S,DH)
    unsigned short* vws = kws + XS;           // (B,H,DH,S)
    unsigned short* ctx = vws + XS;           // (B,S,D) — holds Wq/Wk/Wv bf16 pre-flash

    unsigned short* q0 = (unsigned short*)d_ws;             // [B][S][DH] head-0 q
    unsigned short* k0 = q0 + (size_t)BB * SS * DHH;        // [B][S][DH] head-0 k
    unsigned long long* pm = (unsigned long long*)(k0 + (size_t)BB * SS * DHH); // 1 MB
    float2* stats = (float2*)(pm + (size_t)BB * SS * (SS / 64));                // 32 KB

    // bf16 staging areas in dead regions
    unsigned short* Xq  = (unsigned short*)out_f;           // 8 MB (out region lo)
    unsigned short* Xk  = Xq + XS;                          // 8 MB (out region hi)
    unsigned short* Wqb = ctx;                              // ctx free till flash
    unsigned short* Wkb = Wqb + WSZ;
    unsigned short* Wvb = Wkb + WSZ;
    unsigned short* Wob = qws;                              // qws free after flash

    // q scale = 1/sqrt(DH) * log2(e)  -> exp2-based softmax downstream
    const float qscale = 0.125f * 1.4426950408889634f;

    // 1: q/k conversions + weight conversions + mask pack, one launch
    prep<<<13824, 256, 0, stream>>>(query_, key_, Wq, Wk, Wv,
                                    Xq, Xk, Wqb, Wkb, Wvb, mask_, pm);

    // 2: all three projections in one launch (V converts f32 in-kernel)
    gemm_qkv<<<768, 512, 0, stream>>>(Xq, Xk, value_, Wqb, Wkb, Wvb,
                                      bq, bk, bv, qws, kws, vws, q0, k0, qscale);

    // 3: flash attention (+ head-0 (M,L) stats)
    flash_attn<<<BB * HH * (SS / 128), 512, 0, stream>>>(qws, kws, vws, pm, ctx, stats);

    // 4: Wo -> bf16 (into qws region, dead after flash)
    cvt_bf16<<<WSZ / 2048, 256, 0, stream>>>(Wo, Wob);

    // 5: output projection
    gemm_o<<<256, 512, 0, stream>>>(ctx, Wob, bo, out_f);

    // 6: head-0 probabilities in one pass over the scratch region
    prob_h0<<<512, 256, 0, stream>>>(q0, k0, pm, stats, out_f + XS);
}

// Round 8
// 298.682 us; speedup vs baseline: 1.0342x; 1.0342x over previous
//
#include <hip/hip_runtime.h>

// Problem constants: B=2, S=2048, D=1024, H=16, DH=64
constexpr int BB = 2, SS = 2048, DD = 1024, HH = 16, DHH = 64;

typedef __attribute__((ext_vector_type(4))) float f32x4;
typedef __attribute__((ext_vector_type(8))) __bf16 bf16x8;      // 4 VGPRs, MFMA A/B operand
typedef __attribute__((ext_vector_type(8))) unsigned short us8; // 16B staging vector

__device__ __forceinline__ unsigned short f32_to_bf16(float f) {
    unsigned int u = __float_as_uint(f);
    u += 0x7fffu + ((u >> 16) & 1u);   // round-to-nearest-even
    return (unsigned short)(u >> 16);
}

// packed f32x2 -> bf16x2 (RNE); gfx950 has v_cvt_pk_bf16_f32
__device__ __forceinline__ ushort2 pk_bf16(float a, float b) {
#if __has_builtin(__builtin_amdgcn_cvt_pk_bf16_f32)
    typedef __attribute__((ext_vector_type(2))) __bf16 bf16x2;
    bf16x2 r = __builtin_amdgcn_cvt_pk_bf16_f32(a, b);
    return *(ushort2*)&r;
#else
    ushort2 r; r.x = f32_to_bf16(a); r.y = f32_to_bf16(b); return r;
#endif
}
__device__ __forceinline__ ushort4 pk_bf16x4(float a, float b, float c, float d) {
    const ushort2 lo = pk_bf16(a, b), hi = pk_bf16(c, d);
    ushort4 r; r.x = lo.x; r.y = lo.y; r.z = hi.x; r.w = hi.y;
    return r;
}
__device__ __forceinline__ us8 cvt_us8(float4 a, float4 b) {
    const ushort4 lo = pk_bf16x4(a.x, a.y, a.z, a.w);
    const ushort4 hi = pk_bf16x4(b.x, b.y, b.z, b.w);
    us8 o;
    o[0] = lo.x; o[1] = lo.y; o[2] = lo.z; o[3] = lo.w;
    o[4] = hi.x; o[5] = hi.y; o[6] = hi.z; o[7] = hi.w;
    return o;
}

__device__ __forceinline__ f32x4 mfma_bf16(bf16x8 a, bf16x8 b, f32x4 c) {
    return __builtin_amdgcn_mfma_f32_16x16x32_bf16(a, b, c, 0, 0, 0);
}

// async global->LDS DMA, 16B per lane. LDS dest = wave-uniform base + lane*16.
__device__ __forceinline__ void stage16(const void* g, void* l) {
    typedef const __attribute__((address_space(1))) unsigned int gas_t;
    typedef __attribute__((address_space(3))) unsigned int las_t;
    __builtin_amdgcn_global_load_lds((gas_t*)(unsigned long long)g,
                                     (las_t*)(unsigned int)(unsigned long long)l,
                                     16, 0, 0);
}

// ---------------------------------------------------------------------------
// cvt helper: fp32 -> bf16, 8 elements/thread, one 2048-element block `blk`
// ---------------------------------------------------------------------------
__device__ __forceinline__ void cvt_block(const float* __restrict__ src,
                                          unsigned short* __restrict__ dst, int blk) {
    const size_t i = ((size_t)blk * 256 + threadIdx.x) * 8;
    const float4 a = *(const float4*)(src + i);
    const float4 b = *(const float4*)(src + i + 4);
    *(us8*)(dst + i) = cvt_us8(a, b);
}

// standalone cvt (used for Wo after flash)
__global__ __launch_bounds__(256) void cvt_bf16(const float* __restrict__ src,
                                                unsigned short* __restrict__ dst) {
    cvt_block(src, dst, blockIdx.x);
}

// ---------------------------------------------------------------------------
// prep: ALL pre-gemm prep in one launch (15872 blocks).
//   blocks [0,6144):    cvt query/key/value f32 -> bf16 (2048 blocks each)
//   blocks [6144,7680): cvt Wq/Wk/Wv (512 blocks each)
//   blocks [7680,15872): mask pack (8192 blocks x 16 chunks over 4 iters
//                        = 131072 chunks = B*S*S/64)
// ---------------------------------------------------------------------------
__global__ __launch_bounds__(256) void prep(const float* __restrict__ q,
                                            const float* __restrict__ k,
                                            const float* __restrict__ v,
                                            const float* __restrict__ Wq,
                                            const float* __restrict__ Wk,
                                            const float* __restrict__ Wv,
                                            unsigned short* __restrict__ Xq,
                                            unsigned short* __restrict__ Xk,
                                            unsigned short* __restrict__ Xv,
                                            unsigned short* __restrict__ Wqb,
                                            unsigned short* __restrict__ Wkb,
                                            unsigned short* __restrict__ Wvb,
                                            const int* __restrict__ mask,
                                            unsigned long long* __restrict__ pm) {
    const int id = blockIdx.x;
    if (id < 6144) {
        const int sel = id >> 11, blk = id & 2047;
        cvt_block(sel == 0 ? q : (sel == 1 ? k : v),
                  sel == 0 ? Xq : (sel == 1 ? Xk : Xv), blk);
    } else if (id < 7680) {
        const int wid = id - 6144;
        const int sel = wid >> 9, blk = wid & 511;
        cvt_block(sel == 0 ? Wq : (sel == 1 ? Wk : Wv),
                  sel == 0 ? Wqb : (sel == 1 ? Wkb : Wvb), blk);
    } else {
        const int mid = id - 7680;
        const int t = threadIdx.x, lane = t & 63;
#pragma unroll
        for (int it = 0; it < 4; ++it) {
            const size_t chunk = (size_t)mid * 16 + it * 4 + (t >> 6);
            const int val = mask[chunk * 64 + lane];
            const unsigned long long b = __ballot(val != 0);
            if (lane == 0) pm[chunk] = b;
        }
    }
}

// ---------------------------------------------------------------------------
// NT GEMM body (verified R2-R4): 128x64 tile, BK=64, 4 waves.
// global_load_lds DMA staging, double-buffered, counted vmcnt(6), chunk-XOR
// swizzle (linear DMA dest + pre-swizzled global source + swizzled reads),
// setprio around MFMA. `nid` is the pre-swizzled block id in [0,512).
// mode: 0 = bf16 out (B,H,S,DH) [+ optional head-0 copy], 1 = bf16 out
// (B,H,DH,S), 2 = f32 out (B,S,D).
// ---------------------------------------------------------------------------
__device__ __forceinline__ void gemm_body(int mode,
                                          const unsigned short* __restrict__ A,
                                          const unsigned short* __restrict__ Wb,
                                          const float* __restrict__ bias,
                                          void* __restrict__ outp,
                                          float scale, int nid,
                                          unsigned short* __restrict__ h0) {
    constexpr int K = DD;
    __shared__ __align__(16) unsigned short Ash[2][128][64];
    __shared__ __align__(16) unsigned short Bsh[2][64][64];

    const int n0 = (nid & 15) * 64;
    const int m0 = (nid >> 4) * 128;

    const int t = threadIdx.x;
    const int lane = t & 63, w = t >> 6;
    const int l15 = lane & 15, quad = lane >> 4;
    const int wm = (w >> 1) * 64, wn = (w & 1) * 32;

    // staging source (pre-swizzled). Lane l of issue j fills LDS row
    // (stripe + j*8 + (l>>3)), chunk (l&7); content must be global chunk
    // (l&7) ^ row&7, and row&7 == l>>3 for every issue (j*8 ≡ 0 mod 8).
    const int srow = lane >> 3;                    // 0..7
    const int scol8 = ((lane & 7) ^ srow) * 8;     // pre-swizzled col (bf16 units)
    const unsigned short* Ag = A + (size_t)(m0 + w * 32 + srow) * K + scol8;
    const unsigned short* Bg = Wb + (size_t)(n0 + w * 16 + srow) * K + scol8;

    f32x4 acc[4][2] = {};

    // prologue: K-tile 0 -> buf 0 (6 DMA ops/thread)
#pragma unroll
    for (int j = 0; j < 4; ++j) stage16(Ag + (size_t)j * 8 * K, &Ash[0][w * 32 + j * 8][0]);
#pragma unroll
    for (int j = 0; j < 2; ++j) stage16(Bg + (size_t)j * 8 * K, &Bsh[0][w * 16 + j * 8][0]);

    for (int kk = 0; kk < K / 64; ++kk) {
        const int cur = kk & 1;
        if (kk < K / 64 - 1) {
            const size_t ko = (size_t)(kk + 1) * 64;
#pragma unroll
            for (int j = 0; j < 4; ++j)
                stage16(Ag + (size_t)j * 8 * K + ko, &Ash[cur ^ 1][w * 32 + j * 8][0]);
#pragma unroll
            for (int j = 0; j < 2; ++j)
                stage16(Bg + (size_t)j * 8 * K + ko, &Bsh[cur ^ 1][w * 16 + j * 8][0]);
            // drain current tile's 6 DMA ops; leave the 6 newest in flight
            __asm__ volatile("s_waitcnt vmcnt(6)" ::: "memory");
        } else {
            __asm__ volatile("s_waitcnt vmcnt(0)" ::: "memory");
        }
        __builtin_amdgcn_s_barrier();
        __builtin_amdgcn_sched_barrier(0);

        const unsigned short* Ab = &Ash[cur][0][0];
        const unsigned short* Bb = &Bsh[cur][0][0];

#pragma unroll
        for (int s = 0; s < 2; ++s) {
            const int ch = ((s * 4 + quad) ^ (l15 & 7)) * 8;   // swizzled read chunk
            bf16x8 af[4], bfr[2];
#pragma unroll
            for (int mi = 0; mi < 4; ++mi)
                af[mi] = *(const bf16x8*)&Ab[(wm + mi * 16 + l15) * 64 + ch];
#pragma unroll
            for (int ni = 0; ni < 2; ++ni)
                bfr[ni] = *(const bf16x8*)&Bb[(wn + ni * 16 + l15) * 64 + ch];
            __builtin_amdgcn_s_setprio(1);
#pragma unroll
            for (int mi = 0; mi < 4; ++mi)
#pragma unroll
                for (int ni = 0; ni < 2; ++ni)
                    acc[mi][ni] = mfma_bf16(af[mi], bfr[ni], acc[mi][ni]);
            __builtin_amdgcn_s_setprio(0);
        }
        __builtin_amdgcn_sched_barrier(0);
        __builtin_amdgcn_s_barrier();
        __builtin_amdgcn_sched_barrier(0);
    }

#pragma unroll
    for (int ni = 0; ni < 2; ++ni) {
        const int c = n0 + wn + ni * 16 + l15;
        const float bs = bias[c];
#pragma unroll
        for (int mi = 0; mi < 4; ++mi) {
#pragma unroll
            for (int r = 0; r < 4; ++r) {
                const int mrow = m0 + wm + mi * 16 + quad * 4 + r;
                const float val = (acc[mi][ni][r] + bs) * scale;
                if (mode == 2) {
                    ((float*)outp)[(size_t)mrow * DD + c] = val;
                } else {
                    const int bi2 = mrow >> 11, si = mrow & (SS - 1);
                    const int hi2 = c >> 6, di = c & (DHH - 1);
                    unsigned short* o = (unsigned short*)outp;
                    const unsigned short v16 = f32_to_bf16(val);
                    if (mode == 0) {
                        o[((size_t)(bi2 * HH + hi2) * SS + si) * DHH + di] = v16;
                        if (h0 != nullptr && hi2 == 0)
                            h0[((size_t)bi2 * SS + si) * DHH + di] = v16;  // head-0 copy
                    } else {
                        o[((size_t)(bi2 * HH + hi2) * DHH + di) * SS + si] = v16;
                    }
                }
            }
        }
    }
}

// fused Q + V projection: 1024 blocks (512 each), ~3 blocks/CU resident.
__global__ __launch_bounds__(256) void gemm_qv(const unsigned short* __restrict__ Xq,
                                               const unsigned short* __restrict__ Wqb,
                                               const float* __restrict__ bq,
                                               unsigned short* __restrict__ qws,
                                               float qscale,
                                               unsigned short* __restrict__ q0,
                                               const unsigned short* __restrict__ Xv,
                                               const unsigned short* __restrict__ Wvb,
                                               const float* __restrict__ bv,
                                               unsigned short* __restrict__ vws) {
    const int id = blockIdx.x;
    const int gid = id >> 9, id9 = id & 511;
    const int nid = (id9 & 7) * 64 + (id9 >> 3);           // XCD-chunked, bijective
    gemm_body(gid, gid ? Xv : Xq, gid ? Wvb : Wqb, gid ? bv : bq,
              gid ? (void*)vws : (void*)qws, gid ? 1.0f : qscale, nid,
              gid ? nullptr : q0);
}

// single-gemm wrapper (K projection with head-0 export; output projection)
template <int MODE>
__global__ __launch_bounds__(256) void gemm_one(const unsigned short* __restrict__ A,
                                                const unsigned short* __restrict__ Wb,
                                                const float* __restrict__ bias,
                                                void* __restrict__ outp,
                                                float scale,
                                                unsigned short* __restrict__ h0) {
    const int id = blockIdx.x;
    const int nid = (id & 7) * 64 + (id >> 3);             // XCD-chunked, bijective
    gemm_body(MODE, A, Wb, bias, outp, scale, nid, h0);
}

// ---------------------------------------------------------------------------
// Flash attention v6 (verified R3-R5, byte-identical): 8 waves, 128 q-rows,
// 16 rows/wave; K/V double-buffered via global_load_lds + counted vmcnt(3);
// chunk-XOR swizzle; setprio; defer-max; head-0 (M,L) export; XCD swizzle.
// ---------------------------------------------------------------------------
__global__ __launch_bounds__(512, 4) void flash_attn(const unsigned short* __restrict__ qws,
                                                     const unsigned short* __restrict__ kws,
                                                     const unsigned short* __restrict__ vws,
                                                     const unsigned long long* __restrict__ pm,
                                                     unsigned short* __restrict__ ctx,
                                                     float2* __restrict__ stats) {
    __shared__ __align__(16) unsigned short Ksh[2][64][64];   // [key][d], swizzled
    __shared__ __align__(16) unsigned short Vsh[2][64][64];   // [d][key], swizzled
    __shared__ __align__(16) unsigned short Psh[8][16][72];   // per-wave [q][key]

    constexpr int NQT = SS / 128;                  // 16
    const int id = blockIdx.x;
    const int nid = (id & 7) * 64 + (id >> 3);
    const int qt = nid % NQT;
    const int bh = nid / NQT;
    const int bi = bh / HH, hi = bh % HH;

    const int t = threadIdx.x;
    const int lane = t & 63, w = t >> 6;           // w in 0..7
    const int l15 = lane & 15, quad = lane >> 4;
    const int sh4 = quad * 4;
    const int xk = quad ^ (l15 & 7);               // swizzled chunk for fragment reads

    const unsigned short* qp = qws + (size_t)bh * SS * DHH;
    const unsigned short* kp = kws + (size_t)bh * SS * DHH;
    const unsigned short* vp = vws + (size_t)bh * DHH * SS;

    const int q_loc = qt * 128 + w * 16 + l15;
    const bf16x8 bq0 = *(const bf16x8*)(qp + (size_t)q_loc * DHH + quad * 8);
    const bf16x8 bq1 = *(const bf16x8*)(qp + (size_t)q_loc * DHH + 32 + quad * 8);
    const unsigned long long* pmrow = pm + ((size_t)bi * SS + q_loc) * (SS / 64);

    const int srow = lane >> 3;            // row within wave's 8-row stripe
    const int scol = (lane & 7) ^ srow;    // pre-swizzled source chunk
    const unsigned short* kg = kp + (size_t)(w * 8 + srow) * DHH + scol * 8;
    const unsigned short* vg = vp + (size_t)(w * 8 + srow) * SS + scol * 8;

    f32x4 accO[4] = {};                    // O^T: d = 16i+quad*4+r, q = l15
    float m_run = -1e30f, l_run = 0.f;
    const float NEG_INF = -__builtin_inff();

    unsigned long long mcur = pmrow[0];
    stage16(kg, &Ksh[0][w * 8][0]);        // tile 0 in flight
    stage16(vg, &Vsh[0][w * 8][0]);

    constexpr int NT = SS / 64;
    for (int kt = 0; kt < NT; ++kt) {
        const int cur = kt & 1;
        unsigned long long mnxt = 0;
        if (kt < NT - 1) {
            mnxt = pmrow[kt + 1];                                        // VMEM op #1
            stage16(kg + (size_t)(kt + 1) * 64 * DHH, &Ksh[cur ^ 1][w * 8][0]); // #2
            stage16(vg + (size_t)(kt + 1) * 64,       &Vsh[cur ^ 1][w * 8][0]); // #3
            __asm__ volatile("s_waitcnt vmcnt(3)" ::: "memory");
        } else {
            __asm__ volatile("s_waitcnt vmcnt(0)" ::: "memory");
        }
        __builtin_amdgcn_s_barrier();          // everyone's current tile landed
        __builtin_amdgcn_sched_barrier(0);     // no LDS reads hoist above this

        const unsigned short* Kb = &Ksh[cur][0][0];
        const unsigned short* Vb = &Vsh[cur][0][0];

        bf16x8 ak0[4], ak1[4];
#pragma unroll
        for (int i = 0; i < 4; ++i) {
            ak0[i] = *(const bf16x8*)&Kb[(i * 16 + l15) * 64 + xk * 8];
            ak1[i] = *(const bf16x8*)&Kb[(i * 16 + l15) * 64 + (xk ^ 4) * 8];
        }

        const unsigned int mlo = ((unsigned int)mcur) >> sh4;
        const unsigned int mhi = ((unsigned int)(mcur >> 32)) >> sh4;

        // S^T: key = kt*64 + 16i + quad*4 + r, q = l15
        float sc[4][4];
        __builtin_amdgcn_s_setprio(1);
#pragma unroll
        for (int i = 0; i < 4; ++i) {
            f32x4 s4 = {};
            s4 = mfma_bf16(ak0[i], bq0, s4);
            s4 = mfma_bf16(ak1[i], bq1, s4);
            const unsigned int mw = (i & 2) ? mhi : mlo;
#pragma unroll
            for (int r = 0; r < 4; ++r)
                sc[i][r] = ((mw >> ((i & 1) * 16 + r)) & 1u) ? NEG_INF : s4[r];
        }
        __builtin_amdgcn_s_setprio(0);

        // issue V fragment reads early; latency hides under softmax VALU
        bf16x8 av0[4], av1[4];
#pragma unroll
        for (int i = 0; i < 4; ++i) {
            av0[i] = *(const bf16x8*)&Vb[(i * 16 + l15) * 64 + xk * 8];
            av1[i] = *(const bf16x8*)&Vb[(i * 16 + l15) * 64 + (xk ^ 4) * 8];
        }

        // online softmax for q = l15 (base-2; scores carry log2e)
        float tm = sc[0][0];
#pragma unroll
        for (int i = 0; i < 4; ++i)
#pragma unroll
            for (int r = 0; r < 4; ++r) tm = fmaxf(tm, sc[i][r]);
        tm = fmaxf(tm, __shfl_xor(tm, 16));
        tm = fmaxf(tm, __shfl_xor(tm, 32));

        // defer-max (T13): if no q-row's tile-max exceeds m_run+8, keep the
        // old max -> skip accO rescale. P bounded by 2^8 (safe in bf16).
        const bool nodefer = !__all(tm <= m_run + 8.0f);
        const float mn = nodefer ? fmaxf(m_run, tm) : m_run;

        float rs = 0.f;
#pragma unroll
        for (int i = 0; i < 4; ++i)
#pragma unroll
            for (int r = 0; r < 4; ++r) {
                const float p = __builtin_amdgcn_exp2f(sc[i][r] - mn);
                sc[i][r] = p;
                rs += p;
            }
        rs += __shfl_xor(rs, 16);
        rs += __shfl_xor(rs, 32);

        if (nodefer) {                         // wave-uniform branch
            const float alpha = __builtin_amdgcn_exp2f(m_run - mn);
            l_run = l_run * alpha + rs;
            m_run = mn;
#pragma unroll
            for (int i = 0; i < 4; ++i) accO[i] *= alpha;
        } else {
            l_run += rs;
        }

        // P store: lane's 4 consecutive keys -> one b64 per i (wave-private)
#pragma unroll
        for (int i = 0; i < 4; ++i)
            *(ushort4*)&Psh[w][l15][i * 16 + sh4] =
                pk_bf16x4(sc[i][0], sc[i][1], sc[i][2], sc[i][3]);
        __asm__ volatile("s_waitcnt lgkmcnt(0)" ::: "memory");  // wave-local RAW

        const bf16x8 p0 = *(const bf16x8*)&Psh[w][l15][quad * 8];
        const bf16x8 p1 = *(const bf16x8*)&Psh[w][l15][32 + quad * 8];
        __builtin_amdgcn_s_setprio(1);
#pragma unroll
        for (int i = 0; i < 4; ++i) {
            accO[i] = mfma_bf16(av0[i], p0, accO[i]);   // O^T[d][q]
            accO[i] = mfma_bf16(av1[i], p1, accO[i]);
        }
        __builtin_amdgcn_s_setprio(0);

        __builtin_amdgcn_sched_barrier(0);     // nothing sinks below this point
        __builtin_amdgcn_s_barrier();          // all reads of buf[cur] done
        __builtin_amdgcn_sched_barrier(0);     // next iter's VMEM stays below
        mcur = mnxt;
    }

    // epilogue
    const float inv = 1.0f / l_run;
    unsigned short* cb = ctx + ((size_t)(bi * SS) + q_loc) * DD + hi * DHH;
#pragma unroll
    for (int i = 0; i < 4; ++i)
        *(ushort4*)&cb[i * 16 + sh4] = pk_bf16x4(accO[i][0] * inv, accO[i][1] * inv,
                                                 accO[i][2] * inv, accO[i][3] * inv);

    // head-0: export softmax stats (M, L). p = exp2(s - M)/L is exact even
    // with deferred M (both offsets cancel).
    if (hi == 0 && quad == 0) {
        float2 st; st.x = m_run; st.y = l_run;
        stats[(size_t)bi * SS + q_loc] = st;
    }
}

// ---------------------------------------------------------------------------
// prob_h0 (verified structure): head-0 final probabilities in ONE pass using
// flash's (M, L). Same bf16 operands + MFMA order as flash -> bit-identical
// scores. Masked -> exactly 0.
// Grid: 512 blocks (B * 32 q-tiles * 8 key-chunks of 256), 2 blocks/CU.
// ---------------------------------------------------------------------------
__global__ __launch_bounds__(256) void prob_h0(const unsigned short* __restrict__ q0,
                                               const unsigned short* __restrict__ k0,
                                               const unsigned long long* __restrict__ pm,
                                               const float2* __restrict__ stats,
                                               float* __restrict__ outp) {
    __shared__ __align__(16) unsigned short Ksh[64][72];

    const int id = blockIdx.x;
    const int nid = (id & 7) * 64 + (id >> 3);     // XCD-chunked, bijective
    const int kc = nid & 7;                        // key chunk (256 keys)
    const int qt = (nid >> 3) & 31;                // q tile
    const int bi = nid >> 8;                       // batch

    const int t = threadIdx.x;
    const int lane = t & 63, w = t >> 6;
    const int l15 = lane & 15, quad = lane >> 4;
    const int sh4 = quad * 4;

    const int q = qt * 64 + w * 16 + l15;      // this lane's q row
    const unsigned short* qp = q0 + ((size_t)bi * SS + q) * DHH;
    const bf16x8 bq0 = *(const bf16x8*)(qp + quad * 8);
    const bf16x8 bq1 = *(const bf16x8*)(qp + 32 + quad * 8);

    const unsigned short* kp = k0 + (size_t)bi * SS * DHH;
    const unsigned long long* pmq = pm + ((size_t)bi * SS + q) * (SS / 64);
    float* orow = outp + ((size_t)bi * SS + q) * SS;

    const float2 st = stats[(size_t)bi * SS + q];
    const float M = st.x;
    const float invL = 1.0f / st.y;

    for (int kt = 0; kt < 4; ++kt) {
        const int key0 = kc * 256 + kt * 64;
        __syncthreads();
#pragma unroll
        for (int hf = 0; hf < 2; ++hf) {
            const int v = t + hf * 256;
            const int row = v >> 3, off = (v & 7) * 8;
            *(us8*)&Ksh[row][off] = *(const us8*)(kp + (size_t)(key0 + row) * DHH + off);
        }
        __syncthreads();

        const unsigned long long m64 = pmq[kc * 4 + kt];
        const unsigned int mlo = ((unsigned int)m64) >> sh4;
        const unsigned int mhi = ((unsigned int)(m64 >> 32)) >> sh4;

#pragma unroll
        for (int i = 0; i < 4; ++i) {
            const bf16x8 ak0 = *(const bf16x8*)&Ksh[i * 16 + l15][quad * 8];
            const bf16x8 ak1 = *(const bf16x8*)&Ksh[i * 16 + l15][32 + quad * 8];
            f32x4 s4 = {};
            s4 = mfma_bf16(ak0, bq0, s4);
            s4 = mfma_bf16(ak1, bq1, s4);
            const unsigned int mw = (i & 2) ? mhi : mlo;
            float4 ov;
#pragma unroll
            for (int r = 0; r < 4; ++r) {
                const float p = __builtin_amdgcn_exp2f(s4[r] - M) * invL;
                ((float*)&ov)[r] = ((mw >> ((i & 1) * 16 + r)) & 1u) ? 0.0f : p;
            }
            *(float4*)&orow[key0 + i * 16 + sh4] = ov;
        }
    }
}

// ---------------------------------------------------------------------------
// inputs: 0 key, 1 value, 2 query, 3 mask, 4 Wk, 5 bk, 6 Wv, 7 bv,
//         8 Wq, 9 bq, 10 Wo, 11 bo
// d_out: output (B*S*D f32, 16 MB) ++ top_attn (B*S*S f32, 32 MB)
// d_ws (~2.13 MB): head-0 q/k (1 MB) + packed mask bits (1 MB) + stats (32 KB)
// Memory plan (R4-verified, scratch ALIASES the top_attn region — it must
// never extend past d_out):
//   out_f  (16 MB): Xq (8) + Xk (8)          [dead once Q/K projections read]
//   top    (32 MB): qws 8 | kws 8 (Xv until gemm-K) | vws 8 | ctx 8 (W*b
//                   until flash; Wob lives in qws after flash)
// Graph: 7 nodes (prep, gemm_qv, gemm_k, flash, cvt_Wo, gemm_o, prob_h0).
// ---------------------------------------------------------------------------
extern "C" void kernel_launch(void* const* d_in, const int* in_sizes, int n_in,
                              void* d_out, int out_size, void* d_ws, size_t ws_size,
                              hipStream_t stream) {
    const float* key_   = (const float*)d_in[0];
    const float* value_ = (const float*)d_in[1];
    const float* query_ = (const float*)d_in[2];
    const int*   mask_  = (const int*)d_in[3];
    const float* Wk = (const float*)d_in[4];
    const float* bk = (const float*)d_in[5];
    const float* Wv = (const float*)d_in[6];
    const float* bv = (const float*)d_in[7];
    const float* Wq = (const float*)d_in[8];
    const float* bq = (const float*)d_in[9];
    const float* Wo = (const float*)d_in[10];
    const float* bo = (const float*)d_in[11];

    constexpr size_t XS  = (size_t)BB * SS * DD;  // 4194304 elements
    constexpr size_t WSZ = (size_t)DD * DD;       // 1048576 elements

    float* out_f = (float*)d_out;
    unsigned short* scratch = (unsigned short*)(out_f + XS);  // aliases top_attn
    unsigned short* qws = scratch;            // (B,H,S,DH)
    unsigned short* kws = qws + XS;           // (B,H,S,DH)
    unsigned short* vws = kws + XS;           // (B,H,DH,S)
    unsigned short* ctx = vws + XS;           // (B,S,D) — holds Wq/Wk/Wv bf16 pre-flash

    unsigned short* q0 = (unsigned short*)d_ws;             // [B][S][DH] head-0 q
    unsigned short* k0 = q0 + (size_t)BB * SS * DHH;        // [B][S][DH] head-0 k
    unsigned long long* pm = (unsigned long long*)(k0 + (size_t)BB * SS * DHH); // 1 MB
    float2* stats = (float2*)(pm + (size_t)BB * SS * (SS / 64));                // 32 KB

    // bf16 staging areas in dead regions
    unsigned short* Xq  = (unsigned short*)out_f;           // 8 MB (out region lo)
    unsigned short* Xk  = Xq + XS;                          // 8 MB (out region hi)
    unsigned short* Xv  = kws;                              // kws free till gemm-k
    unsigned short* Wqb = ctx;                              // ctx free till flash
    unsigned short* Wkb = Wqb + WSZ;
    unsigned short* Wvb = Wkb + WSZ;
    unsigned short* Wob = qws;                              // qws free after flash

    // q scale = 1/sqrt(DH) * log2(e)  -> exp2-based softmax downstream
    const float qscale = 0.125f * 1.4426950408889634f;

    // 1: q/k/v conversions + weight conversions + mask pack, one launch
    prep<<<15872, 256, 0, stream>>>(query_, key_, value_, Wq, Wk, Wv,
                                    Xq, Xk, Xv, Wqb, Wkb, Wvb, mask_, pm);

    // 2: fused Q + V projections (V must complete before K overwrites kws)
    gemm_qv<<<1024, 256, 0, stream>>>(Xq, Wqb, bq, qws, qscale, q0,
                                      Xv, Wvb, bv, vws);

    // 3: K projection (+ head-0 k export)
    gemm_one<0><<<512, 256, 0, stream>>>(Xk, Wkb, bk, kws, 1.0f, k0);

    // 4: flash attention (+ head-0 (M,L) stats)
    flash_attn<<<BB * HH * (SS / 128), 512, 0, stream>>>(qws, kws, vws, pm, ctx, stats);

    // 5: Wo -> bf16 (into qws region, dead after flash)
    cvt_bf16<<<WSZ / 2048, 256, 0, stream>>>(Wo, Wob);

    // 6: output projection
    gemm_one<2><<<512, 256, 0, stream>>>(ctx, Wob, bo, out_f, 1.0f, nullptr);

    // 7: head-0 probabilities in one pass over the top_attn / scratch region
    prob_h0<<<512, 256, 0, stream>>>(q0, k0, pm, stats, out_f + XS);
}